// Round 6
// baseline (275.360 us; speedup 1.0000x reference)
//
#include <hip/hip_runtime.h>
#include <hip/hip_bf16.h>
#include <cstdint>

typedef __attribute__((ext_vector_type(8))) short short8;
typedef __attribute__((ext_vector_type(16))) float f32x16;

// Problem constants (B, N, D, H) = (256, 100000, 512, 2048)
constexpr int M   = 256;
constexpr int NTB = 100000;
constexpr int D   = 512;
constexpr int H   = 2048;

constexpr int NSTRIP = NTB / 32;                  // 3125 (exact)
constexpr int WPB    = 4;                         // waves per dist block
constexpr int NBLK_D = (NSTRIP + WPB - 1) / WPB;  // 782
constexpr float EPS_MARGIN = 4.0f;                // ~44 sigma of hi-only bf16 dot error

// ---- ws layout (bytes) ----
constexpr size_t WS_CODES_HI = 0;                                   // 256KB frag-ordered bf16
constexpr size_t WS_KEYS     = 262144;                              // [NSTRIP][256] u64 = 6.4MB
constexpr size_t WS_IDX      = WS_KEYS + (size_t)NSTRIP * 256 * 8;  // 256 u32
constexpr size_t WS_H1       = WS_IDX + 1024;                       // 256*2048 f32

// bf16 helpers (RNE)
__device__ inline unsigned short f2bf_rne(float x) {
  unsigned u = __float_as_uint(x);
  u += 0x7fffu + ((u >> 16) & 1u);
  return (unsigned short)(u >> 16);
}
__device__ inline unsigned long long packkey(float s, unsigned n) {
  unsigned u = __float_as_uint(s);
  u = (u & 0x80000000u) ? ~u : (u | 0x80000000u);  // order-preserving
  return ((unsigned long long)u << 32) | n;
}
__device__ inline float unpackf(unsigned u) {
  u = (u & 0x80000000u) ? (u & 0x7fffffffu) : ~u;
  return __uint_as_float(u);
}
__device__ inline unsigned long long u64min(unsigned long long a, unsigned long long b) {
  return a < b ? a : b;
}

// ---------------- codes -> frag-ordered bf16 hi ----------------
// element (q, k): g=q>>5, s=k>>4, lane=(q&31)|(((k>>3)&1)<<5), j=k&7
// at chi[((g*32+s)*64+lane)*8 + j]
__global__ __launch_bounds__(256) void convert_codes_kernel(
    const float* __restrict__ codes, unsigned short* __restrict__ chi)
{
  const int i = blockIdx.x * 256 + threadIdx.x;  // 0 .. 256*512-1
  const int q = i >> 9, k = i & 511;
  const int g = q >> 5, s = k >> 4;
  const int lane = (q & 31) | (((k >> 3) & 1) << 5);
  const int j = k & 7;
  chi[((size_t)(g * 32 + s) * 64 + (size_t)lane) * 8 + j] = f2bf_rne(codes[i]);
}

// ---------------- barrier-free MFMA dist + per-strip argmin ----------------
// Each wave owns a 32-row table strip x all 256 queries. Table (A operand)
// loads straight from HBM into MFMA fragment layout (row = lane&31,
// k = kt*16 + (lane>>5)*8 + j), converted f32->bf16 in-register. Codes (B)
// stream from the L2-resident pre-swizzled chi. No LDS staging, no
// __syncthreads in the loop: latency hides via per-wave queues + TLP.
__global__ __launch_bounds__(256, 2) void dist_mfma_kernel(
    const float* __restrict__ table,
    const unsigned short* __restrict__ chi,
    unsigned long long* __restrict__ keys)
{
  __shared__ float csqw[WPB][32];

  const int t    = threadIdx.x;
  const int lane = t & 63;
  const int w    = t >> 6;
  const int half = lane >> 5;
  const int r32  = lane & 31;

  int strip = blockIdx.x * WPB + w;
  if (strip >= NSTRIP) strip = NSTRIP - 1;   // dup strips write identical keys
  const int row_base = strip * 32;

  const float* asrc = table + (size_t)(row_base + r32) * D + half * 8;
  const int voff = lane * 8;  // element offset inside a chi frag-block

  f32x16 acc[8];
  #pragma unroll
  for (int nt = 0; nt < 8; ++nt)
    #pragma unroll
    for (int r = 0; r < 16; ++r) acc[nt][r] = 0.f;

  float4 aq[4][2];   // A queue, 4 K-steps deep
  short8 bq[8];      // B buffer, reloaded right after use

  #pragma unroll
  for (int i = 0; i < 4; ++i) {
    aq[i][0] = *(const float4*)(asrc + i * 16);
    aq[i][1] = *(const float4*)(asrc + i * 16 + 4);
  }
  #pragma unroll
  for (int nt = 0; nt < 8; ++nt)
    bq[nt] = *(const short8*)(chi + (size_t)nt * 16384 + voff);

  float csq = 0.f;

  #pragma unroll 4
  for (int kt = 0; kt < 32; ++kt) {
    const int slot = kt & 3;
    short8 aH;
    {
      float xs[8] = {aq[slot][0].x, aq[slot][0].y, aq[slot][0].z, aq[slot][0].w,
                     aq[slot][1].x, aq[slot][1].y, aq[slot][1].z, aq[slot][1].w};
      #pragma unroll
      for (int j = 0; j < 8; ++j) {
        csq += xs[j] * xs[j];
        aH[j] = (short)f2bf_rne(xs[j]);
      }
    }
    if (kt + 4 < 32) {  // refill A queue (4 steps ahead of use)
      aq[slot][0] = *(const float4*)(asrc + (kt + 4) * 16);
      aq[slot][1] = *(const float4*)(asrc + (kt + 4) * 16 + 4);
    }
    #pragma unroll
    for (int nt = 0; nt < 8; ++nt) {
      acc[nt] = __builtin_amdgcn_mfma_f32_32x32x16_bf16(aH, bq[nt], acc[nt], 0, 0, 0);
      if (kt + 1 < 32)
        bq[nt] = *(const short8*)(chi + (size_t)nt * 16384 + (kt + 1) * 512 + voff);
    }
  }

  // exact f32 c_sq per row: halves live in lane and lane^32
  csq += __shfl_xor(csq, 32);
  if (half == 0) csqw[w][r32] = csq;
  __syncthreads();

  float csq_r[16];
  #pragma unroll
  for (int r = 0; r < 16; ++r)
    csq_r[r] = csqw[w][(r & 3) + 8 * (r >> 2) + 4 * half];

  // per-query argmin of score = c_sq - 2*dot (x_sq const per query; sqrt monotone)
  #pragma unroll
  for (int nt = 0; nt < 8; ++nt) {
    unsigned long long best = ~0ull;
    #pragma unroll
    for (int r = 0; r < 16; ++r) {
      const int grow = row_base + (r & 3) + 8 * (r >> 2) + 4 * half;
      const float sc = csq_r[r] - 2.f * acc[nt][r];
      best = u64min(best, packkey(sc, (unsigned)grow));
    }
    best = u64min(best, __shfl_xor(best, 32));
    if (half == 0)
      keys[(size_t)strip * 256 + nt * 32 + r32] = best;
  }
}

// ---------------- merge per-strip minima + margin rescue (exact f32) --------
__global__ __launch_bounds__(256) void merge_rescore_kernel(
    const unsigned long long* __restrict__ keys,
    const float* __restrict__ codes, const float* __restrict__ table,
    unsigned* __restrict__ out_idx)
{
  __shared__ unsigned long long wmin[4];
  __shared__ unsigned long long bestkey_s;
  __shared__ int cand[16];
  __shared__ int ncand;
  __shared__ float redbuf[4];
  __shared__ float bestv_s;
  __shared__ int   besti_s;

  const int q = blockIdx.x, t = threadIdx.x;

  unsigned long long lb = ~0ull;
  for (int i = t; i < NSTRIP; i += 256) lb = u64min(lb, keys[(size_t)i * 256 + q]);
  #pragma unroll
  for (int off = 1; off < 64; off <<= 1) lb = u64min(lb, __shfl_xor(lb, off));
  if ((t & 63) == 0) wmin[t >> 6] = lb;
  __syncthreads();
  if (t == 0) {
    unsigned long long b = u64min(u64min(wmin[0], wmin[1]), u64min(wmin[2], wmin[3]));
    bestkey_s = b;
    cand[0] = (int)(b & 0xffffffffu);
    ncand = 1;
  }
  __syncthreads();
  const unsigned long long bk = bestkey_s;
  const float thr = unpackf((unsigned)(bk >> 32)) + EPS_MARGIN;
  for (int i = t; i < NSTRIP; i += 256) {
    unsigned long long v = keys[(size_t)i * 256 + q];
    if (v != bk && unpackf((unsigned)(v >> 32)) <= thr) {
      int p = atomicAdd(&ncand, 1);
      if (p < 16) cand[p] = (int)(v & 0xffffffffu);
    }
  }
  __syncthreads();
  const int nc = min(ncand, 16);
  if (nc == 1) {
    if (t == 0) out_idx[q] = (unsigned)cand[0];
    return;
  }
  if (t == 0) { bestv_s = INFINITY; besti_s = 0x7fffffff; }
  __syncthreads();
  for (int c = 0; c < nc; ++c) {
    const int n = cand[c];
    const float* crow = table + (size_t)n * D;
    const float* xrow = codes + (size_t)q * D;
    float part = 0.f;
    for (int d = t; d < D; d += 256) part += crow[d] * crow[d] - 2.f * xrow[d] * crow[d];
    #pragma unroll
    for (int off = 1; off < 64; off <<= 1) part += __shfl_xor(part, off);
    if ((t & 63) == 0) redbuf[t >> 6] = part;
    __syncthreads();
    if (t == 0) {
      float tot = redbuf[0] + redbuf[1] + redbuf[2] + redbuf[3];
      if (tot < bestv_s || (tot == bestv_s && n < besti_s)) { bestv_s = tot; besti_s = n; }
    }
    __syncthreads();
  }
  if (t == 0) out_idx[q] = (unsigned)besti_s;
}

// ---------------- Kernel B1: h1 = relu(gather(table, idx) @ w1 + b1) --------
constexpr int BM2 = 64, BN2 = 64, BK2 = 16;

__global__ __launch_bounds__(256) void mlp1_kernel(
    const unsigned* __restrict__ final_idx,
    const float* __restrict__ table,
    const float* __restrict__ w1, const float* __restrict__ b1,
    float* __restrict__ h1)
{
  __shared__ float As[2][BK2][BM2];
  __shared__ float Bs[2][BK2][BN2];
  __shared__ unsigned idx_s[BM2];

  const int t  = threadIdx.x;
  const int tx = t & 15, ty = t >> 4;
  const int h0 = blockIdx.x * BN2;
  const int m0 = blockIdx.y * BM2;

  if (t < BM2) idx_s[t] = final_idx[m0 + t];
  __syncthreads();

  const int mr = t >> 2, c4 = (t & 3) * 4;
  const int dd = t >> 4, cb = (t & 15) * 4;
  const float* arow = table + (size_t)idx_s[mr] * D + c4;
  const float* brow = w1 + (size_t)dd * H + h0 + cb;

  float acc[4][4] = {{0.f}};

  float4 av = *(const float4*)(arow);
  float4 bv = *(const float4*)(brow);
  {
    float a[4] = {av.x, av.y, av.z, av.w};
    #pragma unroll
    for (int j = 0; j < 4; ++j) As[0][c4 + j][mr] = a[j];
    *(float4*)&Bs[0][dd][cb] = bv;
  }
  __syncthreads();

  for (int kt = 0; kt < D / BK2; ++kt) {
    const int cur = kt & 1;
    if (kt < D / BK2 - 1) {
      av = *(const float4*)(arow + (kt + 1) * BK2);
      bv = *(const float4*)(brow + (size_t)(kt + 1) * BK2 * H);
    }
    #pragma unroll
    for (int kk = 0; kk < BK2; ++kk) {
      float4 a4 = *(const float4*)&As[cur][kk][ty * 4];
      float4 b4 = *(const float4*)&Bs[cur][kk][tx * 4];
      float a[4] = {a4.x,a4.y,a4.z,a4.w}, b[4] = {b4.x,b4.y,b4.z,b4.w};
      #pragma unroll
      for (int i = 0; i < 4; ++i)
        #pragma unroll
        for (int j = 0; j < 4; ++j) acc[i][j] += a[i] * b[j];
    }
    if (kt < D / BK2 - 1) {
      float a[4] = {av.x, av.y, av.z, av.w};
      #pragma unroll
      for (int j = 0; j < 4; ++j) As[cur ^ 1][c4 + j][mr] = a[j];
      *(float4*)&Bs[cur ^ 1][dd][cb] = bv;
    }
    __syncthreads();
  }

  #pragma unroll
  for (int i = 0; i < 4; ++i) {
    const int m = m0 + ty * 4 + i;
    float v0 = acc[i][0] + b1[h0 + tx * 4 + 0];
    float v1 = acc[i][1] + b1[h0 + tx * 4 + 1];
    float v2 = acc[i][2] + b1[h0 + tx * 4 + 2];
    float v3 = acc[i][3] + b1[h0 + tx * 4 + 3];
    float4 o;
    o.x = v0 > 0.f ? v0 : 0.f;
    o.y = v1 > 0.f ? v1 : 0.f;
    o.z = v2 > 0.f ? v2 : 0.f;
    o.w = v3 > 0.f ? v3 : 0.f;
    *(float4*)(h1 + (size_t)m * H + h0 + tx * 4) = o;
  }
}

// ---------------- init d_out with biases (clears 0xAA poison) ----------
__global__ void init_out_kernel(const float* __restrict__ b2u,
                                const float* __restrict__ b2s,
                                float* __restrict__ out)
{
  const int i = blockIdx.x * blockDim.x + threadIdx.x;
  if (i < M * D) out[i] = b2u[i & (D - 1)];
  else           out[i] = b2s[i & (D - 1)];
}

// ---------------- Kernel B2: [mu|logstd] += h1 @ [w2u|w2s]  (split-K=4) ----
constexpr int KSPLIT = 4;

__global__ __launch_bounds__(256) void mlp2_kernel(
    const float* __restrict__ h1,
    const float* __restrict__ w2u, const float* __restrict__ w2s,
    float* __restrict__ out)
{
  __shared__ float As[2][BK2][BM2];
  __shared__ float Bs[2][BK2][BN2];

  const int t  = threadIdx.x;
  const int tx = t & 15, ty = t >> 4;
  const int n0 = blockIdx.x * BN2;           // over [w2u|w2s] concat (2*D wide)
  const int m0 = blockIdx.y * BM2;
  const int k0 = blockIdx.z * (H / KSPLIT);  // 512-wide K chunk

  const float* Wn = (n0 < D) ? w2u : w2s;
  const int col0 = n0 & (D - 1);

  const int mr = t >> 2, c4 = (t & 3) * 4;
  const int dd = t >> 4, cb = (t & 15) * 4;
  const float* arow = h1 + (size_t)(m0 + mr) * H + k0 + c4;
  const float* brow = Wn + (size_t)(k0 + dd) * D + col0 + cb;

  float acc[4][4] = {{0.f}};
  constexpr int NITER = (H / KSPLIT) / BK2;  // 32

  float4 av = *(const float4*)(arow);
  float4 bv = *(const float4*)(brow);
  {
    float a[4] = {av.x, av.y, av.z, av.w};
    #pragma unroll
    for (int j = 0; j < 4; ++j) As[0][c4 + j][mr] = a[j];
    *(float4*)&Bs[0][dd][cb] = bv;
  }
  __syncthreads();

  for (int kt = 0; kt < NITER; ++kt) {
    const int cur = kt & 1;
    if (kt < NITER - 1) {
      av = *(const float4*)(arow + (kt + 1) * BK2);
      bv = *(const float4*)(brow + (size_t)(kt + 1) * BK2 * D);
    }
    #pragma unroll
    for (int kk = 0; kk < BK2; ++kk) {
      float4 a4 = *(const float4*)&As[cur][kk][ty * 4];
      float4 b4 = *(const float4*)&Bs[cur][kk][tx * 4];
      float a[4] = {a4.x,a4.y,a4.z,a4.w}, b[4] = {b4.x,b4.y,b4.z,b4.w};
      #pragma unroll
      for (int i = 0; i < 4; ++i)
        #pragma unroll
        for (int j = 0; j < 4; ++j) acc[i][j] += a[i] * b[j];
    }
    if (kt < NITER - 1) {
      float a[4] = {av.x, av.y, av.z, av.w};
      #pragma unroll
      for (int j = 0; j < 4; ++j) As[cur ^ 1][c4 + j][mr] = a[j];
      *(float4*)&Bs[cur ^ 1][dd][cb] = bv;
    }
    __syncthreads();
  }

  #pragma unroll
  for (int i = 0; i < 4; ++i) {
    const int m = m0 + ty * 4 + i;
    const int c = col0 + tx * 4;
    float* dst = (n0 < D) ? (out + (size_t)m * D + c)
                          : (out + (size_t)(M * D) + (size_t)m * D + c);
    #pragma unroll
    for (int j = 0; j < 4; ++j) atomicAdd(dst + j, acc[i][j]);
  }
}

extern "C" void kernel_launch(void* const* d_in, const int* in_sizes, int n_in,
                              void* d_out, int out_size, void* d_ws, size_t ws_size,
                              hipStream_t stream)
{
  const float* codes = (const float*)d_in[0];
  const float* table = (const float*)d_in[1];
  const float* w1    = (const float*)d_in[2];
  const float* b1    = (const float*)d_in[3];
  const float* w2u   = (const float*)d_in[4];
  const float* b2u   = (const float*)d_in[5];
  const float* w2s   = (const float*)d_in[6];
  const float* b2s   = (const float*)d_in[7];
  float* out = (float*)d_out;

  unsigned short* chi = (unsigned short*)((char*)d_ws + WS_CODES_HI);
  unsigned long long* keys = (unsigned long long*)((char*)d_ws + WS_KEYS);
  unsigned* final_idx = (unsigned*)((char*)d_ws + WS_IDX);
  float* h1 = (float*)((char*)d_ws + WS_H1);

  convert_codes_kernel<<<(M * D) / 256, 256, 0, stream>>>(codes, chi);

  dist_mfma_kernel<<<NBLK_D, 256, 0, stream>>>(table, chi, keys);

  merge_rescore_kernel<<<M, 256, 0, stream>>>(keys, codes, table, final_idx);

  dim3 gB1(H / BN2, M / BM2);
  mlp1_kernel<<<gB1, 256, 0, stream>>>(final_idx, table, w1, b1, h1);

  init_out_kernel<<<(2 * M * D) / 256, 256, 0, stream>>>(b2u, b2s, out);

  dim3 gB2((2 * D) / BN2, M / BM2, KSPLIT);
  mlp2_kernel<<<gB2, 256, 0, stream>>>(h1, w2u, w2s, out);
}

// Round 7
// 184.888 us; speedup vs baseline: 1.4893x; 1.4893x over previous
//
#include <hip/hip_runtime.h>
#include <hip/hip_bf16.h>
#include <cstdint>

typedef __attribute__((ext_vector_type(8))) short short8;
typedef __attribute__((ext_vector_type(16))) float f32x16;

// Problem constants (B, N, D, H) = (256, 100000, 512, 2048)
constexpr int M   = 256;
constexpr int NTB = 100000;
constexpr int D   = 512;
constexpr int H   = 2048;

constexpr int NSTRIP = NTB / 32;                  // 3125 (exact)
constexpr int NBLK_D = (NSTRIP + 1) / 2;          // 1563 (2 strips per block)
constexpr float EPS_MARGIN = 4.0f;                // ~44 sigma of hi-only bf16 dot error

// ---- ws layout (bytes) ----
constexpr size_t WS_CODES_HI = 0;                                   // 256KB frag-ordered bf16
constexpr size_t WS_KEYS     = 262144;                              // [NSTRIP][256] u64 = 6.4MB
constexpr size_t WS_IDX      = WS_KEYS + (size_t)NSTRIP * 256 * 8;  // 256 u32
constexpr size_t WS_H1       = WS_IDX + 1024;                       // 256*2048 f32

// bf16 helpers (RNE)
__device__ inline unsigned short f2bf_rne(float x) {
  unsigned u = __float_as_uint(x);
  u += 0x7fffu + ((u >> 16) & 1u);
  return (unsigned short)(u >> 16);
}
__device__ inline unsigned long long packkey(float s, unsigned n) {
  unsigned u = __float_as_uint(s);
  u = (u & 0x80000000u) ? ~u : (u | 0x80000000u);  // order-preserving
  return ((unsigned long long)u << 32) | n;
}
__device__ inline float unpackf(unsigned u) {
  u = (u & 0x80000000u) ? (u & 0x7fffffffu) : ~u;
  return __uint_as_float(u);
}
__device__ inline unsigned long long u64min(unsigned long long a, unsigned long long b) {
  return a < b ? a : b;
}

// ---------------- codes -> frag-ordered bf16 hi ----------------
// element (q, k): g=q>>5, s=k>>4, lane=(q&31)|(((k>>3)&1)<<5), j=k&7
// at chi[((g*32+s)*64+lane)*8 + j]
__global__ __launch_bounds__(256) void convert_codes_kernel(
    const float* __restrict__ codes, unsigned short* __restrict__ chi)
{
  const int i = blockIdx.x * 256 + threadIdx.x;  // 0 .. 256*512-1
  const int q = i >> 9, k = i & 511;
  const int g = q >> 5, s = k >> 4;
  const int lane = (q & 31) | (((k >> 3) & 1) << 5);
  const int j = k & 7;
  chi[((size_t)(g * 32 + s) * 64 + (size_t)lane) * 8 + j] = f2bf_rne(codes[i]);
}

// ---------------- barrier-free MFMA dist + per-strip argmin ----------------
// Block = 4 waves = 2 strips x 2 query-halves. Each wave: 32 table rows x
// 128 queries -> acc = 4 x f32x16 = 64 VGPRs (no spills, ~3 waves/SIMD).
// Wave pair (same strip, other query half) is in the SAME block/CU, so its
// table re-read hits L2 -> HBM traffic stays ~1x table. A loads go straight
// from HBM into MFMA fragment layout (row=lane&31, k=kt*16+(lane>>5)*8+j),
// f32->bf16 in-register. B streams from L2-resident pre-swizzled chi.
// No __syncthreads in the main loop.
__global__ __launch_bounds__(256) void dist_mfma_kernel(
    const float* __restrict__ table,
    const unsigned short* __restrict__ chi,
    unsigned long long* __restrict__ keys)
{
  __shared__ float csqw[4][32];

  const int t    = threadIdx.x;
  const int lane = t & 63;
  const int w    = t >> 6;       // 0..3
  const int half = lane >> 5;
  const int r32  = lane & 31;
  const int qh   = w & 1;        // query half: queries qh*128 .. qh*128+127

  int strip = blockIdx.x * 2 + (w >> 1);
  if (strip >= NSTRIP) strip = NSTRIP - 1;   // dup strips write identical keys
  const int row_base = strip * 32;

  const float* asrc = table + (size_t)(row_base + r32) * D + half * 8;
  const unsigned short* bbase = chi + (size_t)qh * 4 * 16384 + (size_t)lane * 8;

  f32x16 acc[4];
  #pragma unroll
  for (int nt = 0; nt < 4; ++nt)
    #pragma unroll
    for (int r = 0; r < 16; ++r) acc[nt][r] = 0.f;

  float4 aq[4][2];   // A queue, 4 K-steps deep (static idx via full unroll)
  short8 bq[4];      // current B fragments
  short8 bnx[4];     // next-step B fragments (prefetched before MFMAs)

  #pragma unroll
  for (int i = 0; i < 4; ++i) {
    aq[i][0] = *(const float4*)(asrc + i * 16);
    aq[i][1] = *(const float4*)(asrc + i * 16 + 4);
  }
  #pragma unroll
  for (int nt = 0; nt < 4; ++nt)
    bq[nt] = *(const short8*)(bbase + (size_t)nt * 16384);

  float csq = 0.f;

  #pragma unroll 4
  for (int kt = 0; kt < 32; ++kt) {
    const int slot = kt & 3;
    short8 aH;
    {
      float xs[8] = {aq[slot][0].x, aq[slot][0].y, aq[slot][0].z, aq[slot][0].w,
                     aq[slot][1].x, aq[slot][1].y, aq[slot][1].z, aq[slot][1].w};
      #pragma unroll
      for (int j = 0; j < 8; ++j) {
        csq += xs[j] * xs[j];
        aH[j] = (short)f2bf_rne(xs[j]);
      }
    }
    if (kt + 4 < 32) {  // refill A queue (4 steps ahead of use)
      aq[slot][0] = *(const float4*)(asrc + (kt + 4) * 16);
      aq[slot][1] = *(const float4*)(asrc + (kt + 4) * 16 + 4);
    }
    if (kt + 1 < 32) {  // prefetch next B fragments; overlap with MFMAs below
      #pragma unroll
      for (int nt = 0; nt < 4; ++nt)
        bnx[nt] = *(const short8*)(bbase + (size_t)nt * 16384 + (kt + 1) * 512);
    }
    #pragma unroll
    for (int nt = 0; nt < 4; ++nt)
      acc[nt] = __builtin_amdgcn_mfma_f32_32x32x16_bf16(aH, bq[nt], acc[nt], 0, 0, 0);
    if (kt + 1 < 32) {
      #pragma unroll
      for (int nt = 0; nt < 4; ++nt) bq[nt] = bnx[nt];
    }
  }

  // exact f32 c_sq per row: halves live in lane and lane^32
  csq += __shfl_xor(csq, 32);
  if (half == 0) csqw[w][r32] = csq;
  __syncthreads();

  float csq_r[16];
  #pragma unroll
  for (int r = 0; r < 16; ++r)
    csq_r[r] = csqw[w][(r & 3) + 8 * (r >> 2) + 4 * half];

  // per-query argmin of score = c_sq - 2*dot (x_sq const per query; sqrt monotone)
  #pragma unroll
  for (int nt = 0; nt < 4; ++nt) {
    unsigned long long best = ~0ull;
    #pragma unroll
    for (int r = 0; r < 16; ++r) {
      const int grow = row_base + (r & 3) + 8 * (r >> 2) + 4 * half;
      const float sc = csq_r[r] - 2.f * acc[nt][r];
      best = u64min(best, packkey(sc, (unsigned)grow));
    }
    best = u64min(best, __shfl_xor(best, 32));
    if (half == 0)
      keys[(size_t)strip * 256 + (qh * 4 + nt) * 32 + r32] = best;
  }
}

// ---------------- merge per-strip minima + margin rescue (exact f32) --------
__global__ __launch_bounds__(256) void merge_rescore_kernel(
    const unsigned long long* __restrict__ keys,
    const float* __restrict__ codes, const float* __restrict__ table,
    unsigned* __restrict__ out_idx)
{
  __shared__ unsigned long long wmin[4];
  __shared__ unsigned long long bestkey_s;
  __shared__ int cand[16];
  __shared__ int ncand;
  __shared__ float redbuf[4];
  __shared__ float bestv_s;
  __shared__ int   besti_s;

  const int q = blockIdx.x, t = threadIdx.x;

  unsigned long long lb = ~0ull;
  for (int i = t; i < NSTRIP; i += 256) lb = u64min(lb, keys[(size_t)i * 256 + q]);
  #pragma unroll
  for (int off = 1; off < 64; off <<= 1) lb = u64min(lb, __shfl_xor(lb, off));
  if ((t & 63) == 0) wmin[t >> 6] = lb;
  __syncthreads();
  if (t == 0) {
    unsigned long long b = u64min(u64min(wmin[0], wmin[1]), u64min(wmin[2], wmin[3]));
    bestkey_s = b;
    cand[0] = (int)(b & 0xffffffffu);
    ncand = 1;
  }
  __syncthreads();
  const unsigned long long bk = bestkey_s;
  const float thr = unpackf((unsigned)(bk >> 32)) + EPS_MARGIN;
  for (int i = t; i < NSTRIP; i += 256) {
    unsigned long long v = keys[(size_t)i * 256 + q];
    if (v != bk && unpackf((unsigned)(v >> 32)) <= thr) {
      int p = atomicAdd(&ncand, 1);
      if (p < 16) cand[p] = (int)(v & 0xffffffffu);
    }
  }
  __syncthreads();
  const int nc = min(ncand, 16);
  if (nc == 1) {
    if (t == 0) out_idx[q] = (unsigned)cand[0];
    return;
  }
  if (t == 0) { bestv_s = INFINITY; besti_s = 0x7fffffff; }
  __syncthreads();
  for (int c = 0; c < nc; ++c) {
    const int n = cand[c];
    const float* crow = table + (size_t)n * D;
    const float* xrow = codes + (size_t)q * D;
    float part = 0.f;
    for (int d = t; d < D; d += 256) part += crow[d] * crow[d] - 2.f * xrow[d] * crow[d];
    #pragma unroll
    for (int off = 1; off < 64; off <<= 1) part += __shfl_xor(part, off);
    if ((t & 63) == 0) redbuf[t >> 6] = part;
    __syncthreads();
    if (t == 0) {
      float tot = redbuf[0] + redbuf[1] + redbuf[2] + redbuf[3];
      if (tot < bestv_s || (tot == bestv_s && n < besti_s)) { bestv_s = tot; besti_s = n; }
    }
    __syncthreads();
  }
  if (t == 0) out_idx[q] = (unsigned)besti_s;
}

// ---------------- Kernel B1: h1 = relu(gather(table, idx) @ w1 + b1) --------
constexpr int BM2 = 64, BN2 = 64, BK2 = 16;

__global__ __launch_bounds__(256) void mlp1_kernel(
    const unsigned* __restrict__ final_idx,
    const float* __restrict__ table,
    const float* __restrict__ w1, const float* __restrict__ b1,
    float* __restrict__ h1)
{
  __shared__ float As[2][BK2][BM2];
  __shared__ float Bs[2][BK2][BN2];
  __shared__ unsigned idx_s[BM2];

  const int t  = threadIdx.x;
  const int tx = t & 15, ty = t >> 4;
  const int h0 = blockIdx.x * BN2;
  const int m0 = blockIdx.y * BM2;

  if (t < BM2) idx_s[t] = final_idx[m0 + t];
  __syncthreads();

  const int mr = t >> 2, c4 = (t & 3) * 4;
  const int dd = t >> 4, cb = (t & 15) * 4;
  const float* arow = table + (size_t)idx_s[mr] * D + c4;
  const float* brow = w1 + (size_t)dd * H + h0 + cb;

  float acc[4][4] = {{0.f}};

  float4 av = *(const float4*)(arow);
  float4 bv = *(const float4*)(brow);
  {
    float a[4] = {av.x, av.y, av.z, av.w};
    #pragma unroll
    for (int j = 0; j < 4; ++j) As[0][c4 + j][mr] = a[j];
    *(float4*)&Bs[0][dd][cb] = bv;
  }
  __syncthreads();

  for (int kt = 0; kt < D / BK2; ++kt) {
    const int cur = kt & 1;
    if (kt < D / BK2 - 1) {
      av = *(const float4*)(arow + (kt + 1) * BK2);
      bv = *(const float4*)(brow + (size_t)(kt + 1) * BK2 * H);
    }
    #pragma unroll
    for (int kk = 0; kk < BK2; ++kk) {
      float4 a4 = *(const float4*)&As[cur][kk][ty * 4];
      float4 b4 = *(const float4*)&Bs[cur][kk][tx * 4];
      float a[4] = {a4.x,a4.y,a4.z,a4.w}, b[4] = {b4.x,b4.y,b4.z,b4.w};
      #pragma unroll
      for (int i = 0; i < 4; ++i)
        #pragma unroll
        for (int j = 0; j < 4; ++j) acc[i][j] += a[i] * b[j];
    }
    if (kt < D / BK2 - 1) {
      float a[4] = {av.x, av.y, av.z, av.w};
      #pragma unroll
      for (int j = 0; j < 4; ++j) As[cur ^ 1][c4 + j][mr] = a[j];
      *(float4*)&Bs[cur ^ 1][dd][cb] = bv;
    }
    __syncthreads();
  }

  #pragma unroll
  for (int i = 0; i < 4; ++i) {
    const int m = m0 + ty * 4 + i;
    float v0 = acc[i][0] + b1[h0 + tx * 4 + 0];
    float v1 = acc[i][1] + b1[h0 + tx * 4 + 1];
    float v2 = acc[i][2] + b1[h0 + tx * 4 + 2];
    float v3 = acc[i][3] + b1[h0 + tx * 4 + 3];
    float4 o;
    o.x = v0 > 0.f ? v0 : 0.f;
    o.y = v1 > 0.f ? v1 : 0.f;
    o.z = v2 > 0.f ? v2 : 0.f;
    o.w = v3 > 0.f ? v3 : 0.f;
    *(float4*)(h1 + (size_t)m * H + h0 + tx * 4) = o;
  }
}

// ---------------- init d_out with biases (clears 0xAA poison) ----------
__global__ void init_out_kernel(const float* __restrict__ b2u,
                                const float* __restrict__ b2s,
                                float* __restrict__ out)
{
  const int i = blockIdx.x * blockDim.x + threadIdx.x;
  if (i < M * D) out[i] = b2u[i & (D - 1)];
  else           out[i] = b2s[i & (D - 1)];
}

// ---------------- Kernel B2: [mu|logstd] += h1 @ [w2u|w2s]  (split-K=4) ----
constexpr int KSPLIT = 4;

__global__ __launch_bounds__(256) void mlp2_kernel(
    const float* __restrict__ h1,
    const float* __restrict__ w2u, const float* __restrict__ w2s,
    float* __restrict__ out)
{
  __shared__ float As[2][BK2][BM2];
  __shared__ float Bs[2][BK2][BN2];

  const int t  = threadIdx.x;
  const int tx = t & 15, ty = t >> 4;
  const int n0 = blockIdx.x * BN2;           // over [w2u|w2s] concat (2*D wide)
  const int m0 = blockIdx.y * BM2;
  const int k0 = blockIdx.z * (H / KSPLIT);  // 512-wide K chunk

  const float* Wn = (n0 < D) ? w2u : w2s;
  const int col0 = n0 & (D - 1);

  const int mr = t >> 2, c4 = (t & 3) * 4;
  const int dd = t >> 4, cb = (t & 15) * 4;
  const float* arow = h1 + (size_t)(m0 + mr) * H + k0 + c4;
  const float* brow = Wn + (size_t)(k0 + dd) * D + col0 + cb;

  float acc[4][4] = {{0.f}};
  constexpr int NITER = (H / KSPLIT) / BK2;  // 32

  float4 av = *(const float4*)(arow);
  float4 bv = *(const float4*)(brow);
  {
    float a[4] = {av.x, av.y, av.z, av.w};
    #pragma unroll
    for (int j = 0; j < 4; ++j) As[0][c4 + j][mr] = a[j];
    *(float4*)&Bs[0][dd][cb] = bv;
  }
  __syncthreads();

  for (int kt = 0; kt < NITER; ++kt) {
    const int cur = kt & 1;
    if (kt < NITER - 1) {
      av = *(const float4*)(arow + (kt + 1) * BK2);
      bv = *(const float4*)(brow + (size_t)(kt + 1) * BK2 * D);
    }
    #pragma unroll
    for (int kk = 0; kk < BK2; ++kk) {
      float4 a4 = *(const float4*)&As[cur][kk][ty * 4];
      float4 b4 = *(const float4*)&Bs[cur][kk][tx * 4];
      float a[4] = {a4.x,a4.y,a4.z,a4.w}, b[4] = {b4.x,b4.y,b4.z,b4.w};
      #pragma unroll
      for (int i = 0; i < 4; ++i)
        #pragma unroll
        for (int j = 0; j < 4; ++j) acc[i][j] += a[i] * b[j];
    }
    if (kt < NITER - 1) {
      float a[4] = {av.x, av.y, av.z, av.w};
      #pragma unroll
      for (int j = 0; j < 4; ++j) As[cur ^ 1][c4 + j][mr] = a[j];
      *(float4*)&Bs[cur ^ 1][dd][cb] = bv;
    }
    __syncthreads();
  }

  #pragma unroll
  for (int i = 0; i < 4; ++i) {
    const int m = m0 + ty * 4 + i;
    const int c = col0 + tx * 4;
    float* dst = (n0 < D) ? (out + (size_t)m * D + c)
                          : (out + (size_t)(M * D) + (size_t)m * D + c);
    #pragma unroll
    for (int j = 0; j < 4; ++j) atomicAdd(dst + j, acc[i][j]);
  }
}

extern "C" void kernel_launch(void* const* d_in, const int* in_sizes, int n_in,
                              void* d_out, int out_size, void* d_ws, size_t ws_size,
                              hipStream_t stream)
{
  const float* codes = (const float*)d_in[0];
  const float* table = (const float*)d_in[1];
  const float* w1    = (const float*)d_in[2];
  const float* b1    = (const float*)d_in[3];
  const float* w2u   = (const float*)d_in[4];
  const float* b2u   = (const float*)d_in[5];
  const float* w2s   = (const float*)d_in[6];
  const float* b2s   = (const float*)d_in[7];
  float* out = (float*)d_out;

  unsigned short* chi = (unsigned short*)((char*)d_ws + WS_CODES_HI);
  unsigned long long* keys = (unsigned long long*)((char*)d_ws + WS_KEYS);
  unsigned* final_idx = (unsigned*)((char*)d_ws + WS_IDX);
  float* h1 = (float*)((char*)d_ws + WS_H1);

  convert_codes_kernel<<<(M * D) / 256, 256, 0, stream>>>(codes, chi);

  dist_mfma_kernel<<<NBLK_D, 256, 0, stream>>>(table, chi, keys);

  merge_rescore_kernel<<<M, 256, 0, stream>>>(keys, codes, table, final_idx);

  dim3 gB1(H / BN2, M / BM2);
  mlp1_kernel<<<gB1, 256, 0, stream>>>(final_idx, table, w1, b1, h1);

  init_out_kernel<<<(2 * M * D) / 256, 256, 0, stream>>>(b2u, b2s, out);

  dim3 gB2((2 * D) / BN2, M / BM2, KSPLIT);
  mlp2_kernel<<<gB2, 256, 0, stream>>>(h1, w2u, w2s, out);
}